// Round 1
// baseline (214.026 us; speedup 1.0000x reference)
//
#include <hip/hip_runtime.h>

// out[n] = const * exp(-( d @ cov @ d )),  d = x[n] - mean
// x: [N,2] f32, mean: [2] f32, cov: [2,2] f32, const: [1] f32, out: [N] f32.
// Memory-bound: 12 B/point. Strategy: 4 points/thread/iter via 2x float4 load
// + 1x float4 store, grid-stride, 2048 blocks x 256 threads.

__global__ __launch_bounds__(256) void GaussMonom_kernel(
    const float4* __restrict__ x4,   // [N/2] float4: each holds 2 points
    const float*  __restrict__ mean, // [2]
    const float*  __restrict__ cov,  // [4]
    const float*  __restrict__ cst,  // [1]
    float4*       __restrict__ out4, // [N/4]
    const float*  __restrict__ x,    // scalar view (tail)
    float*        __restrict__ out,  // scalar view (tail)
    int n_groups,                    // N/4
    int n_points)                    // N
{
    // Uniform (wave-invariant) parameter loads — L1/scalar-cached, negligible.
    const float m0  = mean[0];
    const float m1  = mean[1];
    const float c00 = cov[0];
    const float c01 = cov[1] + cov[2];  // d0*d1 cross term combined
    const float c11 = cov[3];
    const float k   = cst[0];

    const int gid    = blockIdx.x * blockDim.x + threadIdx.x;
    const int stride = gridDim.x * blockDim.x;

    for (int i = gid; i < n_groups; i += stride) {
        // Two float4 loads = 4 points (x0,y0,x1,y1),(x2,y2,x3,y3)
        const float4 a = x4[2 * i];
        const float4 b = x4[2 * i + 1];
        float4 r;
        {
            const float d0 = a.x - m0, d1 = a.y - m1;
            const float z  = fmaf(d0, fmaf(c00, d0, c01 * d1), c11 * d1 * d1);
            r.x = k * __expf(-z);
        }
        {
            const float d0 = a.z - m0, d1 = a.w - m1;
            const float z  = fmaf(d0, fmaf(c00, d0, c01 * d1), c11 * d1 * d1);
            r.y = k * __expf(-z);
        }
        {
            const float d0 = b.x - m0, d1 = b.y - m1;
            const float z  = fmaf(d0, fmaf(c00, d0, c01 * d1), c11 * d1 * d1);
            r.z = k * __expf(-z);
        }
        {
            const float d0 = b.z - m0, d1 = b.w - m1;
            const float z  = fmaf(d0, fmaf(c00, d0, c01 * d1), c11 * d1 * d1);
            r.w = k * __expf(-z);
        }
        out4[i] = r;
    }

    // Tail (N % 4 != 0) — no-op for N = 16,777,216 but kept for generality.
    for (int i = n_groups * 4 + gid; i < n_points; i += stride) {
        const float d0 = x[2 * i]     - m0;
        const float d1 = x[2 * i + 1] - m1;
        const float z  = fmaf(d0, fmaf(c00, d0, c01 * d1), c11 * d1 * d1);
        out[i] = k * __expf(-z);
    }
}

extern "C" void kernel_launch(void* const* d_in, const int* in_sizes, int n_in,
                              void* d_out, int out_size, void* d_ws, size_t ws_size,
                              hipStream_t stream) {
    const float* x    = (const float*)d_in[0];  // [N,2]
    const float* mean = (const float*)d_in[1];  // [2]
    const float* cov  = (const float*)d_in[2];  // [2,2]
    const float* cst  = (const float*)d_in[3];  // [1]
    float* out        = (float*)d_out;          // [N]

    const int n_points = in_sizes[0] / 2;
    const int n_groups = n_points / 4;

    const int threads = 256;
    int blocks = (n_groups + threads - 1) / threads;
    if (blocks > 2048) blocks = 2048;
    if (blocks < 1) blocks = 1;

    GaussMonom_kernel<<<blocks, threads, 0, stream>>>(
        (const float4*)x, mean, cov, cst,
        (float4*)out, x, out, n_groups, n_points);
}

// Round 2
// 214.009 us; speedup vs baseline: 1.0001x; 1.0001x over previous
//
#include <hip/hip_runtime.h>

// out[n] = const * exp(-( d @ cov @ d )),  d = x[n] - mean
// x: [N,2] f32, mean: [2] f32, cov: [2,2] f32, const: [1] f32, out: [N] f32.
//
// Memory-bound: 12 B/point (201 MB total, L3-resident). Unit-stride access:
// each thread processes one float4 (= 2 points) per chunk, two chunks per
// iteration at a blockDim offset for ILP. Loads: 16 B/lane contiguous.
// Stores: 8 B/lane contiguous (float2).

__global__ __launch_bounds__(256) void GaussMonom_kernel(
    const float4* __restrict__ x4,   // [N/2] float4: each holds 2 points
    const float*  __restrict__ mean, // [2]
    const float*  __restrict__ cov,  // [4]
    const float*  __restrict__ cst,  // [1]
    float2*       __restrict__ out2, // [N/2] float2
    const float*  __restrict__ x,    // scalar view (tail)
    float*        __restrict__ out,  // scalar view (tail)
    int n_f4,                        // N/2 (number of float4 chunks)
    int n_points)                    // N
{
    const float m0  = mean[0];
    const float m1  = mean[1];
    const float c00 = cov[0];
    const float c01 = cov[1] + cov[2];  // combined cross term
    const float c11 = cov[3];
    const float k   = cst[0];

    const int tid    = blockIdx.x * (blockDim.x * 2) + threadIdx.x;
    const int stride = gridDim.x * (blockDim.x * 2);

    // Main loop: two unit-stride float4 chunks per thread per iteration.
    int i = tid;
    for (; i + (int)blockDim.x < n_f4; i += stride) {
        const int j = i + blockDim.x;
        const float4 a = x4[i];
        const float4 b = x4[j];

        float2 ra, rb;
        {
            const float d0 = a.x - m0, d1 = a.y - m1;
            const float z  = fmaf(d0, fmaf(c00, d0, c01 * d1), c11 * d1 * d1);
            ra.x = k * __expf(-z);
        }
        {
            const float d0 = a.z - m0, d1 = a.w - m1;
            const float z  = fmaf(d0, fmaf(c00, d0, c01 * d1), c11 * d1 * d1);
            ra.y = k * __expf(-z);
        }
        {
            const float d0 = b.x - m0, d1 = b.y - m1;
            const float z  = fmaf(d0, fmaf(c00, d0, c01 * d1), c11 * d1 * d1);
            rb.x = k * __expf(-z);
        }
        {
            const float d0 = b.z - m0, d1 = b.w - m1;
            const float z  = fmaf(d0, fmaf(c00, d0, c01 * d1), c11 * d1 * d1);
            rb.y = k * __expf(-z);
        }
        out2[i] = ra;
        out2[j] = rb;
    }
    // Remainder float4 chunks (when n_f4 not divisible by the paired stride).
    for (; i < n_f4; i += stride) {
        const float4 a = x4[i];
        float2 ra;
        {
            const float d0 = a.x - m0, d1 = a.y - m1;
            const float z  = fmaf(d0, fmaf(c00, d0, c01 * d1), c11 * d1 * d1);
            ra.x = k * __expf(-z);
        }
        {
            const float d0 = a.z - m0, d1 = a.w - m1;
            const float z  = fmaf(d0, fmaf(c00, d0, c01 * d1), c11 * d1 * d1);
            ra.y = k * __expf(-z);
        }
        out2[i] = ra;
    }

    // Scalar tail for odd point counts (no-op for N = 16,777,216).
    const int done = n_f4 * 2;
    for (int p = done + blockIdx.x * blockDim.x + threadIdx.x; p < n_points;
         p += gridDim.x * blockDim.x) {
        const float d0 = x[2 * p]     - m0;
        const float d1 = x[2 * p + 1] - m1;
        const float z  = fmaf(d0, fmaf(c00, d0, c01 * d1), c11 * d1 * d1);
        out[p] = k * __expf(-z);
    }
}

extern "C" void kernel_launch(void* const* d_in, const int* in_sizes, int n_in,
                              void* d_out, int out_size, void* d_ws, size_t ws_size,
                              hipStream_t stream) {
    const float* x    = (const float*)d_in[0];  // [N,2]
    const float* mean = (const float*)d_in[1];  // [2]
    const float* cov  = (const float*)d_in[2];  // [2,2]
    const float* cst  = (const float*)d_in[3];  // [1]
    float* out        = (float*)d_out;          // [N]

    const int n_points = in_sizes[0] / 2;
    const int n_f4     = n_points / 2;          // float4 chunks (2 points each)

    const int threads = 256;
    // Each thread covers 2 chunks per iteration.
    long long want = ((long long)n_f4 + threads * 2 - 1) / (threads * 2);
    int blocks = (int)(want > 2048 ? 2048 : (want < 1 ? 1 : want));

    GaussMonom_kernel<<<blocks, threads, 0, stream>>>(
        (const float4*)x, mean, cov, cst,
        (float2*)out, x, out, n_f4, n_points);
}